// Round 8
// baseline (131.585 us; speedup 1.0000x reference)
//
#include <hip/hip_runtime.h>

#define HW    3136
#define HDIM  56
#define CIN   256
#define CR    64
#define NG    16
#define KK    49
#define BEPS  1e-5f

// ---- fused-kernel geometry: block = (gq of 4 g, row, col-half 28, b) ----
#define CHALF 28
#define XC    36            // 28 + 6 halo + 2 pad (left pad = 4 cols)
#define XBUF  4608          // 8 rowx x 16 cg x 36 cols (dwords) per buffer
#define WSTR  36            // w_lds tap-row stride, dwords
#define TSTR  72            // t_lds row stride, shorts

typedef __attribute__((ext_vector_type(8))) short short8;
typedef __attribute__((ext_vector_type(4))) float f32x4;

__device__ __forceinline__ unsigned short f2bf(float f) {
    union { float f; unsigned u; } v; v.f = f;
    unsigned r = (v.u + 0x7FFFu + ((v.u >> 16) & 1u)) >> 16;
    return (unsigned short)r;
}

// Async global->LDS DMA, 16B/lane. Dest = wave-uniform base + lane*16.
__device__ __forceinline__ void gload_lds16(const float* gp, float* lp) {
    __builtin_amdgcn_global_load_lds(
        (const __attribute__((address_space(1))) void*)gp,
        (__attribute__((address_space(3))) void*)lp, 16, 0, 0);
}

// k0: W1b[o][c]=bf16(W1*scale); W2bT[g][tap pad64][c]; b1f = folded BN bias.
__global__ __launch_bounds__(256) void k0_prep(
    const float* __restrict__ W1, const float* __restrict__ b1,
    const float* __restrict__ gamma, const float* __restrict__ beta,
    const float* __restrict__ mean, const float* __restrict__ var,
    const float* __restrict__ W2,
    unsigned short* __restrict__ W1b, unsigned short* __restrict__ W2bT,
    float* __restrict__ b1f)
{
    int idx = blockIdx.x * 256 + threadIdx.x;
    if (idx < CR * CIN) {
        int o = idx >> 8;
        float s = gamma[o] * rsqrtf(var[o] + BEPS);
        W1b[idx] = f2bf(W1[idx] * s);
    } else if (idx < CR * CIN + NG * 64 * 64) {
        int j = idx - CR * CIN;
        int c = j & 63, tap = (j >> 6) & 63, g = j >> 12;
        float v = (tap < KK) ? W2[(g * KK + tap) * CR + c] : 0.f;
        W2bT[j] = f2bf(v);
    } else if (idx < CR * CIN + NG * 64 * 64 + CR) {
        int o = idx - CR * CIN - NG * 64 * 64;
        float s = gamma[o] * rsqrtf(var[o] + BEPS);
        b1f[o] = b1[o] * s + beta[o] - mean[o] * s;
    }
}

// Fused v2: R7 structure with the g-loop split across 4 blocks (gq owns
// g = gq*4..gq*4+3). Grid 448 -> 1792 blocks (7/CU, 3 resident) — R7's 16%
// occupancy / 12% VALU showed the block was latency-starved at 1.75/CU.
// conv1 recomputed per block (x4, ~1 us/CU, L2-hit). XCD chunking: each XCD
// owns exactly one (chalf,b) -> its whole x window (~1.8 MB) is L2-resident;
// the 4 conv1-duplicate blocks are consecutive on the same XCD.
__global__ __launch_bounds__(256, 3) void k2_fused(
    const float* __restrict__ x, const unsigned short* __restrict__ W1b,
    const float* __restrict__ b1f, const unsigned short* __restrict__ W2bT,
    const float* __restrict__ b2, float* __restrict__ out)
{
    __shared__ unsigned short t_lds[32 * TSTR];      // 4.5 KB (rows 28-31 junk)
    __shared__ float w_lds[KK * WSTR];               // 6.9 KB
    __shared__ float x_lds[2 * XBUF];                // 36.9 KB  (total 48.3 KB)

    const int tid = threadIdx.x;
    const int lane = tid & 63, l15 = lane & 15, q = lane >> 4;
    const int wid = tid >> 6;

    // XCD-chunked swizzle: 1792 = 8*224, bijective. Within an XCD chunk:
    // gq fastest (conv1 dups adjacent), then rows; cb = chunk = (chalf,b).
    const int p   = blockIdx.x + 448 * blockIdx.y;
    const int ord = (p & 7) * 224 + (p >> 3);
    const int gq  = ord & 3;                 // g-range = gq*4 .. gq*4+3
    const int h0  = (ord >> 2) % 56;
    const int cb  = ord / 224;
    const int c0  = (cb & 1) * CHALF;
    const int b   = cb >> 1;
    const int g0  = gq * 4;

    // ---- one-time zero of BOTH x buffers (invalid slots stay 0 forever) ----
#pragma unroll
    for (int k = 0; k < 9; k++)
        *(float4*)&x_lds[(k * 256 + tid) * 4] = make_float4(0.f, 0.f, 0.f, 0.f);
    asm volatile("s_waitcnt lgkmcnt(0)" ::: "memory");

    // ---- prologue DMA: x[g0] -> buffer 0 (all 4 waves, 18 groups) ----
#pragma unroll
    for (int k = 0; k < 5; k++) {
        int i = wid + 4 * k;
        if (i < 18) {
            int slot = i * 64 + lane;
            int s = slot % 9, rc = slot / 9;
            int cg = rc & 15, rowx = rc >> 4;
            int hy = h0 - 3 + rowx, gx = c0 + 4 * s - 4;
            if (rowx < 7 && hy >= 0 && hy < HDIM && gx >= 0 && gx <= HDIM - 4)
                gload_lds16(&x[((size_t)b * CIN + g0 * 16 + cg) * HW + hy * HDIM + gx],
                            &x_lds[i * 256]);
        }
    }

    // ---- conv1: waves 0,1 -> t-tile (28 px x 64 Cr), K=256, overlaps DMA ----
    if (wid < 2) {
        int col = wid * 16 + l15; if (col > 27) col = 27;   // tile1 lanes 12-15 dup
        const float* xp = x + (size_t)b * CIN * HW + h0 * HDIM + c0 + col;
        f32x4 acc[4];
#pragma unroll
        for (int nt = 0; nt < 4; nt++) acc[nt] = (f32x4){0.f, 0.f, 0.f, 0.f};
#pragma unroll
        for (int kc = 0; kc < 8; kc++) {
            short8 af;
#pragma unroll
            for (int j = 0; j < 8; j++)
                af[j] = (short)f2bf(xp[(size_t)(kc * 32 + q * 8 + j) * HW]);
#pragma unroll
            for (int nt = 0; nt < 4; nt++) {
                short8 bf = *(const short8*)&W1b[(size_t)(16 * nt + l15) * CIN + kc * 32 + q * 8];
                acc[nt] = __builtin_amdgcn_mfma_f32_16x16x32_bf16(af, bf, acc[nt], 0, 0, 0);
            }
        }
#pragma unroll
        for (int nt = 0; nt < 4; nt++) {
            float bias = b1f[16 * nt + l15];
#pragma unroll
            for (int r = 0; r < 4; r++) {
                float v = fmaxf(acc[nt][r] + bias, 0.f);
                t_lds[(wid * 16 + 4 * q + r) * TSTR + 16 * nt + l15] = f2bf(v);
            }
        }
    }
    __syncthreads();    // t ready; x[g0] DMA drained

    // ---- g-loop (4 iters): phaseA -> bar -> phaseB || DMA x[g+1] -> bar ----
#pragma unroll 2
    for (int gi = 0; gi < 4; ++gi) {
        const int g = g0 + gi;
        const int buf = (gi & 1) * XBUF;

        if (wid < 2) {   // ---- phase A: kgen MFMA, M=28, N=64 taps, K=64 ----
            short8 bfr[4][2];
#pragma unroll
            for (int nt = 0; nt < 4; nt++)
#pragma unroll
                for (int ks = 0; ks < 2; ks++)
                    bfr[nt][ks] = *(const short8*)&W2bT[((size_t)g * 64 + 16 * nt + l15) * 64 + ks * 32 + q * 8];
            float b2v[4];
#pragma unroll
            for (int nt = 0; nt < 4; nt++) {
                int tap = 16 * nt + l15;
                b2v[nt] = (tap < KK) ? b2[g * KK + tap] : 0.f;
            }
            short8 a0 = *(const short8*)&t_lds[(wid * 16 + l15) * TSTR + q * 8];
            short8 a1 = *(const short8*)&t_lds[(wid * 16 + l15) * TSTR + 32 + q * 8];
            const int c4 = wid * 16 + 4 * q;
#pragma unroll
            for (int nt = 0; nt < 4; nt++) {
                f32x4 acc = (f32x4){0.f, 0.f, 0.f, 0.f};
                acc = __builtin_amdgcn_mfma_f32_16x16x32_bf16(a0, bfr[nt][0], acc, 0, 0, 0);
                acc = __builtin_amdgcn_mfma_f32_16x16x32_bf16(a1, bfr[nt][1], acc, 0, 0, 0);
                int tap = 16 * nt + l15;
                if (tap < KK && c4 < CHALF)
                    *(float4*)&w_lds[tap * WSTR + c4] =
                        make_float4(acc[0] + b2v[nt], acc[1] + b2v[nt],
                                    acc[2] + b2v[nt], acc[3] + b2v[nt]);
            }
        }
        __syncthreads();    // w ready

        if (tid < 112) {    // ---- phase B: involution, thread = (cg, quad) ----
            const int cg = tid & 15, quad = tid >> 4;     // quad 0..6
            const int colb = quad * 4;
            float acc[4] = {0.f, 0.f, 0.f, 0.f};
#pragma unroll
            for (int di = 0; di < 7; di++) {
                float wv[7][4];
#pragma unroll
                for (int dj = 0; dj < 7; dj++) {
                    float4 wq = *(const float4*)&w_lds[(di * 7 + dj) * WSTR + colb];
                    wv[dj][0] = wq.x; wv[dj][1] = wq.y; wv[dj][2] = wq.z; wv[dj][3] = wq.w;
                }
                const float* xr = &x_lds[buf + (di * 16 + cg) * XC + colb];
                float4 A  = *(const float4*)&xr[0];
                float4 Bv = *(const float4*)&xr[4];
                float4 Cv = *(const float4*)&xr[8];
                float win[12] = {A.x, A.y, A.z, A.w, Bv.x, Bv.y, Bv.z, Bv.w,
                                 Cv.x, Cv.y, Cv.z, Cv.w};
#pragma unroll
                for (int dj = 0; dj < 7; dj++)
#pragma unroll
                    for (int kk = 0; kk < 4; kk++)
                        acc[kk] += win[kk + dj + 1] * wv[dj][kk];
            }
            float* op = &out[((size_t)b * CIN + g * 16 + cg) * HW + h0 * HDIM + c0 + colb];
            *(float4*)op = make_float4(acc[0], acc[1], acc[2], acc[3]);
        } else if (wid >= 2 && gi + 1 < 4) {
            // ---- waves 2,3: DMA x[g+1] into the other buffer (window = phase B)
            const int nbuf = ((gi + 1) & 1) * XBUF;
            const int wid2 = wid - 2;
#pragma unroll
            for (int k = 0; k < 9; k++) {
                int i = wid2 + 2 * k;
                int slot = i * 64 + lane;
                int s = slot % 9, rc = slot / 9;
                int cg = rc & 15, rowx = rc >> 4;
                int hy = h0 - 3 + rowx, gx = c0 + 4 * s - 4;
                if (rowx < 7 && hy >= 0 && hy < HDIM && gx >= 0 && gx <= HDIM - 4)
                    gload_lds16(&x[((size_t)b * CIN + (g + 1) * 16 + cg) * HW + hy * HDIM + gx],
                                &x_lds[nbuf + i * 256]);
            }
        }
        __syncthreads();    // x[g+1] drained; w free for next phase A
    }
}

extern "C" void kernel_launch(void* const* d_in, const int* in_sizes, int n_in,
                              void* d_out, int out_size, void* d_ws, size_t ws_size,
                              hipStream_t stream) {
    const float* x     = (const float*)d_in[0];
    const float* W1    = (const float*)d_in[1];
    const float* b1    = (const float*)d_in[2];
    const float* gamma = (const float*)d_in[3];
    const float* beta  = (const float*)d_in[4];
    const float* mean  = (const float*)d_in[5];
    const float* var   = (const float*)d_in[6];
    const float* W2    = (const float*)d_in[7];
    const float* b2    = (const float*)d_in[8];
    float* out = (float*)d_out;

    unsigned short* W1b  = (unsigned short*)d_ws;          // 16384 ushorts
    unsigned short* W2bT = W1b + CR * CIN;                 // 65536 ushorts
    float* b1f           = (float*)(W2bT + NG * 64 * 64);  // 64 floats

    int n_k0 = CR * CIN + NG * 64 * 64 + CR;
    k0_prep<<<(n_k0 + 255) / 256, 256, 0, stream>>>(
        W1, b1, gamma, beta, mean, var, W2, W1b, W2bT, b1f);

    dim3 g2(448, 4);     // 1792 blocks: gq(4) x rows(56) x chalf(2) x b(4)
    k2_fused<<<g2, 256, 0, stream>>>(x, W1b, b1f, W2bT, b2, out);
}

// Round 10
// 111.531 us; speedup vs baseline: 1.1798x; 1.1798x over previous
//
#include <hip/hip_runtime.h>

#define HW    3136
#define HDIM  56
#define CIN   256
#define CR    64
#define NG    16
#define KK    49
#define BEPS  1e-5f

// ---- k2 geometry: block = (band of 2 rows, col-half of 28, g, b), 16 cg ----
#define RB     2
#define NBAND  28
#define CHALF  28
#define WSTR   60            // 2*CHALF + 4 pad floats
#define XR     8             // RB + 6 halo rows
#define XC     36            // CHALF + 6 halo + 2 pad (left pad = 4)
#define XCG    16
#define XTOT   (XR * XCG * XC)   // 4608 dwords = 1152 float4 slots
#define NSLOT  1152
#define K1X    (HW / 16)     // 196 conv blocks in k1
#define K1PREP 32            // extra k1 blocks that prep W2bT

typedef __attribute__((ext_vector_type(8))) short short8;
typedef __attribute__((ext_vector_type(4))) float f32x4;

__device__ __forceinline__ unsigned short f2bf(float f) {
    union { float f; unsigned u; } v; v.f = f;
    unsigned r = (v.u + 0x7FFFu + ((v.u >> 16) & 1u)) >> 16;
    return (unsigned short)r;
}

// k1: conv1 MFMA with on-the-fly W1*scale -> bf16 (k0 removed). 196 conv
// blocks + 32 prep blocks that fill W2bT[g][tap pad64][c] for k2.
// Conv: 128 thr = 2 waves splitting K=256; LDS reduce (stride 17, no conflict).
__global__ __launch_bounds__(128) void k1_gemm(
    const float* __restrict__ x, const float* __restrict__ W1,
    const float* __restrict__ b1, const float* __restrict__ gamma,
    const float* __restrict__ beta, const float* __restrict__ mean,
    const float* __restrict__ var, const float* __restrict__ W2,
    unsigned short* __restrict__ t_bf, unsigned short* __restrict__ W2bT)
{
    const int tid = threadIdx.x;
    const int b = blockIdx.y;

    if (blockIdx.x >= K1X) {             // ---- W2bT prep blocks ----
        if (b) return;
        int i = (blockIdx.x - K1X) * 128 + tid;      // 0..4095
#pragma unroll
        for (int r = 0; r < 16; r++) {
            int j = r * 4096 + i;
            int c = j & 63, tap = (j >> 6) & 63, g = j >> 12;
            float v = (tap < KK) ? W2[((size_t)g * KK + tap) * CR + c] : 0.f;
            W2bT[j] = f2bf(v);
        }
        return;
    }

    __shared__ float red[64 * 17];   // 4.25 KB

    const int lane = tid & 63, l15 = lane & 15, q = lane >> 4;
    const int wid = tid >> 6;            // 0/1 = K-half
    const int pxb = blockIdx.x * 16;
    const int kb = wid * 128;            // channel base for this wave

    const float* xp = x + (size_t)b * CIN * HW + pxb + l15;

    // folded BN scale/bias per output channel (loads issue early)
    float sc[4], bias[4];
#pragma unroll
    for (int nt = 0; nt < 4; nt++) {
        int o = 16 * nt + l15;
        float s = gamma[o] * rsqrtf(var[o] + BEPS);
        sc[nt] = s;
        bias[nt] = b1[o] * s + beta[o] - mean[o] * s;
    }

    f32x4 acc[4];
#pragma unroll
    for (int nt = 0; nt < 4; nt++) acc[nt] = (f32x4){0.f, 0.f, 0.f, 0.f};

#pragma unroll
    for (int kc = 0; kc < 4; kc++) {
        short8 af;
#pragma unroll
        for (int j = 0; j < 8; j++)
            af[j] = (short)f2bf(xp[(size_t)(kb + kc * 32 + q * 8 + j) * HW]);
#pragma unroll
        for (int nt = 0; nt < 4; nt++) {
            const float* wp = &W1[(size_t)(16 * nt + l15) * CIN + kb + kc * 32 + q * 8];
            float4 wa = *(const float4*)wp;
            float4 wb = *(const float4*)(wp + 4);
            short8 bf;
            bf[0] = (short)f2bf(wa.x * sc[nt]); bf[1] = (short)f2bf(wa.y * sc[nt]);
            bf[2] = (short)f2bf(wa.z * sc[nt]); bf[3] = (short)f2bf(wa.w * sc[nt]);
            bf[4] = (short)f2bf(wb.x * sc[nt]); bf[5] = (short)f2bf(wb.y * sc[nt]);
            bf[6] = (short)f2bf(wb.z * sc[nt]); bf[7] = (short)f2bf(wb.w * sc[nt]);
            acc[nt] = __builtin_amdgcn_mfma_f32_16x16x32_bf16(af, bf, acc[nt], 0, 0, 0);
        }
    }

    if (wid == 1) {
#pragma unroll
        for (int nt = 0; nt < 4; nt++)
#pragma unroll
            for (int r = 0; r < 4; r++)
                red[lane * 17 + nt * 4 + r] = acc[nt][r];
    }
    __syncthreads();
    if (wid == 0) {
#pragma unroll
        for (int nt = 0; nt < 4; nt++) {
#pragma unroll
            for (int r = 0; r < 4; r++) {
                int px = pxb + 4 * q + r;
                float v = acc[nt][r] + red[lane * 17 + nt * 4 + r] + bias[nt];
                t_bf[((size_t)b * HW + px) * CR + 16 * nt + l15] = f2bf(fmaxf(v, 0.f));
            }
        }
    }
}

// k2 v3 (session-best configuration, 111.7 us total):
//  1. phase-A globals (W2bT frags, t_bf, b2) issue FIRST -> MFMA waits only on
//     them (vmcnt counting), x loads stay in flight underneath.
//  2. x staging = 1152 float4 slots (5 vec loads/thread), held in registers
//     through phase A, ds_write'd just before the barrier.
//  3. single barrier, 224-thread phase B.
__global__ __launch_bounds__(256, 5) void k2_fused(
    const float* __restrict__ x, const unsigned short* __restrict__ t_bf,
    const unsigned short* __restrict__ W2bT, const float* __restrict__ b2,
    float* __restrict__ out)
{
    __shared__ float w_lds[KK * WSTR];               // 11.76 KB
    __shared__ float x_lds[XTOT];                    // 18.43 KB

    const int tid = threadIdx.x;
    const int band = blockIdx.x >> 1, chalf = blockIdx.x & 1;
    const int g = blockIdx.y, b = blockIdx.z;
    const int h0 = band * RB, c0 = chalf * CHALF;
    const int lane = tid & 63, l15 = lane & 15, q = lane >> 4;
    const int wid = tid >> 6;

    // ---- phase-A global loads FIRST ----
    short8 bfr[4][2];
#pragma unroll
    for (int nt = 0; nt < 4; nt++)
#pragma unroll
        for (int ks = 0; ks < 2; ks++)
            bfr[nt][ks] = *(const short8*)&W2bT[((size_t)g * 64 + 16 * nt + l15) * 64 + ks * 32 + q * 8];

    const int arow = wid >> 1, aseg = wid & 1;
    int apx = (h0 + arow) * HDIM + c0 + aseg * 16 + l15;
    if (apx > HW - 1) apx = HW - 1;      // right-edge A rows: garbage, never stored
    const unsigned short* tp = &t_bf[((size_t)b * HW + apx) * CR];
    short8 a0 = *(const short8*)&tp[q * 8];
    short8 a1 = *(const short8*)&tp[32 + q * 8];

    float b2v[4];
#pragma unroll
    for (int nt = 0; nt < 4; nt++) {
        int tap = 16 * nt + l15;
        b2v[nt] = (tap < KK) ? b2[g * KK + tap] : 0.f;
    }

    // ---- x staging loads issue now; consumed (ds_write) after phase A.
    //      slot idx <-> x_lds[4*idx]; [rowx 8][cg 16][9 float4-slots], borders 0.
    float4 xv[5];
#pragma unroll
    for (int it = 0; it < 5; it++) {
        xv[it] = make_float4(0.f, 0.f, 0.f, 0.f);
        if (it < 4 || tid < 128) {
            int idx = it * 256 + tid;
            int s = idx % 9, rc = idx / 9;
            int cg = rc & 15, rowx = rc >> 4;
            int hy = h0 - 3 + rowx, gx = c0 + 4 * s - 4;
            if (hy >= 0 && hy < HDIM && gx >= 0 && gx <= HDIM - 4)
                xv[it] = *(const float4*)&x[((size_t)b * CIN + g * 16 + cg) * HW + hy * HDIM + gx];
        }
    }

    // ---- phase A: kgen MFMA, M = 2 rows x 28 cols, N=64 taps, K=64 ----
    {
        const int cl = aseg * 16 + 4 * q;
#pragma unroll
        for (int nt = 0; nt < 4; nt++) {
            f32x4 acc = (f32x4){0.f, 0.f, 0.f, 0.f};
            acc = __builtin_amdgcn_mfma_f32_16x16x32_bf16(a0, bfr[nt][0], acc, 0, 0, 0);
            acc = __builtin_amdgcn_mfma_f32_16x16x32_bf16(a1, bfr[nt][1], acc, 0, 0, 0);
            int tap = 16 * nt + l15;
            if (tap < KK && cl < CHALF) {
                *(float4*)&w_lds[tap * WSTR + arow * CHALF + cl] =
                    make_float4(acc[0] + b2v[nt], acc[1] + b2v[nt],
                                acc[2] + b2v[nt], acc[3] + b2v[nt]);
            }
        }
    }

    // ---- write staged x to LDS ----
#pragma unroll
    for (int it = 0; it < 5; it++) {
        if (it < 4 || tid < 128) {
            int idx = it * 256 + tid;
            *(float4*)&x_lds[idx * 4] = xv[it];
        }
    }
    __syncthreads();

    // ---- phase B: involution. 224 threads: cg(16) x row(2) x quad(7) ----
    if (tid < 224) {
        const int cg   = tid & 15;
        const int rq   = tid >> 4;          // 0..13
        const int row  = rq & 1;
        const int quad = rq >> 1;           // 0..6
        const int colb = quad * 4, h = h0 + row;

        float acc[4] = {0.f, 0.f, 0.f, 0.f};

#pragma unroll
        for (int di = 0; di < 7; di++) {
            float wv[7][4];
#pragma unroll
            for (int dj = 0; dj < 7; dj++) {
                float4 wq = *(const float4*)&w_lds[(di * 7 + dj) * WSTR + row * CHALF + colb];
                wv[dj][0] = wq.x; wv[dj][1] = wq.y; wv[dj][2] = wq.z; wv[dj][3] = wq.w;
            }
            const float* xr = &x_lds[((row + di) * 16 + cg) * XC + colb];
            float4 A  = *(const float4*)&xr[0];
            float4 Bv = *(const float4*)&xr[4];
            float4 Cv = *(const float4*)&xr[8];
            float win[12] = {A.x, A.y, A.z, A.w, Bv.x, Bv.y, Bv.z, Bv.w,
                             Cv.x, Cv.y, Cv.z, Cv.w};
#pragma unroll
            for (int dj = 0; dj < 7; dj++)
#pragma unroll
                for (int kk = 0; kk < 4; kk++)
                    acc[kk] += win[kk + dj + 1] * wv[dj][kk];
        }
        float* op = &out[((size_t)b * CIN + g * 16 + cg) * HW + h * HDIM + c0 + colb];
        *(float4*)op = make_float4(acc[0], acc[1], acc[2], acc[3]);
    }
}

extern "C" void kernel_launch(void* const* d_in, const int* in_sizes, int n_in,
                              void* d_out, int out_size, void* d_ws, size_t ws_size,
                              hipStream_t stream) {
    const float* x     = (const float*)d_in[0];
    const float* W1    = (const float*)d_in[1];
    const float* b1    = (const float*)d_in[2];
    const float* gamma = (const float*)d_in[3];
    const float* beta  = (const float*)d_in[4];
    const float* mean  = (const float*)d_in[5];
    const float* var   = (const float*)d_in[6];
    const float* W2    = (const float*)d_in[7];
    const float* b2    = (const float*)d_in[8];
    float* out = (float*)d_out;

    unsigned short* t_bf = (unsigned short*)d_ws;          // 802816 ushorts
    unsigned short* W2bT = t_bf + (size_t)4 * HW * CR;     // 65536 ushorts

    dim3 g1(K1X + K1PREP, 4);
    k1_gemm<<<g1, 128, 0, stream>>>(x, W1, b1, gamma, beta, mean, var, W2,
                                    t_bf, W2bT);

    dim3 g2(NBAND * 2, NG, 4);
    k2_fused<<<g2, 256, 0, stream>>>(x, t_bf, W2bT, b2, out);
}